// Round 1
// baseline (1159.473 us; speedup 1.0000x reference)
//
#include <hip/hip_runtime.h>

#define NN 50000
#define NE 800000
#define IN_CH 64
#define HID 128
#define NL 4
#define LN_EPS 1e-5f

// ---------------- preprocessing ----------------

__global__ void k_deg_cnt(const int* __restrict__ ei, const float* __restrict__ ew,
                          float* __restrict__ deg, int* __restrict__ cnt) {
    int e = blockIdx.x * blockDim.x + threadIdx.x;
    if (e >= NE) return;
    int d = ei[NE + e];
    atomicAdd(&deg[d], ew[e]);
    atomicAdd(&cnt[d], 1);
}

// in-place: deg[n] -> dinv[n] = rsqrt(deg[n] + 1)   (self-loop weight 1; always > 0)
__global__ void k_dinv(float* __restrict__ deg) {
    int n = blockIdx.x * blockDim.x + threadIdx.x;
    if (n >= NN) return;
    deg[n] = rsqrtf(deg[n] + 1.0f);
}

// single-block exclusive scan of cnt[NN] -> rowp[NN+1]
__global__ void k_scan(const int* __restrict__ cnt, int* __restrict__ rowp) {
    __shared__ int sm[1024];
    __shared__ int carry_s;
    int tid = threadIdx.x;
    if (tid == 0) carry_s = 0;
    __syncthreads();
    for (int base = 0; base < NN; base += 1024) {
        int i = base + tid;
        int v = (i < NN) ? cnt[i] : 0;
        sm[tid] = v;
        __syncthreads();
        for (int off = 1; off < 1024; off <<= 1) {
            int t = (tid >= off) ? sm[tid - off] : 0;
            __syncthreads();
            sm[tid] += t;
            __syncthreads();
        }
        int incl = sm[tid];
        int carry = carry_s;
        if (i < NN) rowp[i] = carry + incl - v;   // exclusive
        __syncthreads();
        if (tid == 1023) carry_s = carry + incl;  // chunk total
        __syncthreads();
    }
    if (tid == 0) rowp[NN] = carry_s;
}

__global__ void k_scatter(const int* __restrict__ ei, const float* __restrict__ ew,
                          const float* __restrict__ dinv, const int* __restrict__ rowp,
                          int* __restrict__ fill, int* __restrict__ col,
                          float* __restrict__ val) {
    int e = blockIdx.x * blockDim.x + threadIdx.x;
    if (e >= NE) return;
    int s = ei[e];
    int d = ei[NE + e];
    int pos = rowp[d] + atomicAdd(&fill[d], 1);
    col[pos] = s;
    val[pos] = dinv[s] * ew[e] * dinv[d];
}

// ---------------- input projection: h = relu(x @ W_in + b_in) ----------------
// thread = output channel c (128/block), block handles 128 nodes; W_in[:,c] in regs.
#define NPB 128
__global__ __launch_bounds__(128) void k_inproj(const float* __restrict__ x,
                                                const float* __restrict__ W,
                                                const float* __restrict__ b,
                                                float* __restrict__ h) {
    __shared__ float xrow[IN_CH];
    int c = threadIdx.x;
    float w[IN_CH];
#pragma unroll
    for (int k = 0; k < IN_CH; k++) w[k] = W[k * HID + c];
    float bc = b[c];
    int nbeg = blockIdx.x * NPB;
    int nend = min(nbeg + NPB, NN);
    for (int n = nbeg; n < nend; n++) {
        __syncthreads();
        if (c < IN_CH) xrow[c] = x[n * IN_CH + c];
        __syncthreads();
        float acc = 0.f;
        const float4* x4 = (const float4*)xrow;
#pragma unroll
        for (int k4 = 0; k4 < IN_CH / 4; k4++) {
            float4 xv = x4[k4];
            acc += xv.x * w[4 * k4] + xv.y * w[4 * k4 + 1] +
                   xv.z * w[4 * k4 + 2] + xv.w * w[4 * k4 + 3];
        }
        h[n * HID + c] = fmaxf(acc + bc, 0.f);
    }
}

// ---------------- per-layer GEMM: m = h @ W_l ----------------
__global__ __launch_bounds__(128) void k_gemm(const float* __restrict__ h,
                                              const float* __restrict__ W,
                                              float* __restrict__ m) {
    __shared__ float hrow[HID];
    int c = threadIdx.x;
    float w[HID];
#pragma unroll
    for (int k = 0; k < HID; k++) w[k] = W[k * HID + c];
    int nbeg = blockIdx.x * NPB;
    int nend = min(nbeg + NPB, NN);
    for (int n = nbeg; n < nend; n++) {
        __syncthreads();
        hrow[c] = h[n * HID + c];
        __syncthreads();
        float acc = 0.f;
        const float4* h4 = (const float4*)hrow;
#pragma unroll
        for (int k4 = 0; k4 < HID / 4; k4++) {
            float4 hv = h4[k4];
            acc += hv.x * w[4 * k4] + hv.y * w[4 * k4 + 1] +
                   hv.z * w[4 * k4 + 2] + hv.w * w[4 * k4 + 3];
        }
        m[n * HID + c] = acc;
    }
}

// ---------------- aggregate + bias + LN + relu + residual (in-place h) ----------------
__global__ __launch_bounds__(128) void k_agg(const float* __restrict__ m,
                                             const int* __restrict__ rowp,
                                             const int* __restrict__ col,
                                             const float* __restrict__ val,
                                             const float* __restrict__ dinv,
                                             const float* __restrict__ cb,
                                             const float* __restrict__ g,
                                             const float* __restrict__ bb,
                                             float* __restrict__ h) {
    int n = blockIdx.x;
    int c = threadIdx.x;
    float dn = dinv[n];
    float acc = dn * dn * m[n * HID + c];   // self-loop term
    int e0 = rowp[n], e1 = rowp[n + 1];
    for (int e = e0; e < e1; e++) {
        int s = col[e];
        float v = val[e];
        acc += v * m[s * HID + c];
    }
    acc += cb[c];
    // LayerNorm over the 128 channels (2 waves)
    float s1 = acc, s2 = acc * acc;
#pragma unroll
    for (int off = 32; off > 0; off >>= 1) {
        s1 += __shfl_down(s1, off, 64);
        s2 += __shfl_down(s2, off, 64);
    }
    __shared__ float red[4];
    int lane = c & 63, wid = c >> 6;
    if (lane == 0) { red[wid] = s1; red[2 + wid] = s2; }
    __syncthreads();
    float t1 = red[0] + red[1];
    float t2 = red[2] + red[3];
    float mu = t1 * (1.0f / HID);
    float var = t2 * (1.0f / HID) - mu * mu;
    float r = rsqrtf(var + LN_EPS);
    float o = (acc - mu) * r * g[c] + bb[c];
    o = fmaxf(o, 0.f);
    h[n * HID + c] = o + h[n * HID + c];    // residual, in-place
}

// ---------------- launch ----------------

extern "C" void kernel_launch(void* const* d_in, const int* in_sizes, int n_in,
                              void* d_out, int out_size, void* d_ws, size_t ws_size,
                              hipStream_t stream) {
    const float* x    = (const float*)d_in[0];
    const int*   ei   = (const int*)d_in[1];
    const float* ew   = (const float*)d_in[2];
    const float* W_in = (const float*)d_in[3];
    const float* b_in = (const float*)d_in[4];
    const float* cW   = (const float*)d_in[5];
    const float* cb   = (const float*)d_in[6];
    const float* lg   = (const float*)d_in[7];
    const float* lb   = (const float*)d_in[8];
    float* h = (float*)d_out;

    char* ws = (char*)d_ws;
    float* deg  = (float*)(ws + 0);        // 50000 f32, becomes dinv in-place
    int*   cnt  = (int*)  (ws + 200192);   // 50000 i32
    int*   fill = (int*)  (ws + 400384);   // 50000 i32
    int*   rowp = (int*)  (ws + 600576);   // 50001 i32
    int*   col  = (int*)  (ws + 800768);   // 800000 i32
    float* val  = (float*)(ws + 4000768);  // 800000 f32
    float* m    = (float*)(ws + 7200768);  // 50000*128 f32

    // zero deg, cnt, fill (contiguous prefix)
    hipMemsetAsync(d_ws, 0, 600576, stream);

    k_deg_cnt<<<(NE + 255) / 256, 256, 0, stream>>>(ei, ew, deg, cnt);
    k_dinv<<<(NN + 255) / 256, 256, 0, stream>>>(deg);
    k_scan<<<1, 1024, 0, stream>>>(cnt, rowp);
    k_scatter<<<(NE + 255) / 256, 256, 0, stream>>>(ei, ew, deg, rowp, fill, col, val);

    k_inproj<<<(NN + NPB - 1) / NPB, 128, 0, stream>>>(x, W_in, b_in, h);

    for (int l = 0; l < NL; l++) {
        k_gemm<<<(NN + NPB - 1) / NPB, 128, 0, stream>>>(h, cW + l * HID * HID, m);
        k_agg<<<NN, 128, 0, stream>>>(m, rowp, col, val, deg,
                                      cb + l * HID, lg + l * HID, lb + l * HID, h);
    }
}

// Round 2
// 702.346 us; speedup vs baseline: 1.6509x; 1.6509x over previous
//
#include <hip/hip_runtime.h>

#define NN 50000
#define NE 800000
#define IN_CH 64
#define HID 128
#define NL 4
#define LN_EPS 1e-5f

// ---------------- preprocessing ----------------

__global__ void k_deg_cnt(const int* __restrict__ ei, const float* __restrict__ ew,
                          float* __restrict__ deg, int* __restrict__ cnt) {
    int e = blockIdx.x * blockDim.x + threadIdx.x;
    if (e >= NE) return;
    int d = ei[NE + e];
    atomicAdd(&deg[d], ew[e]);
    atomicAdd(&cnt[d], 1);
}

// in-place: deg[n] -> dinv[n] = rsqrt(deg[n] + 1)   (self-loop weight 1; always > 0)
__global__ void k_dinv(float* __restrict__ deg) {
    int n = blockIdx.x * blockDim.x + threadIdx.x;
    if (n >= NN) return;
    deg[n] = rsqrtf(deg[n] + 1.0f);
}

// single-block exclusive scan of cnt[NN] -> rowp[NN+1], wave-shuffle based
__global__ __launch_bounds__(1024) void k_scan(const int* __restrict__ cnt,
                                               int* __restrict__ rowp) {
    __shared__ int wsum[16];
    __shared__ int carry_s;
    int tid = threadIdx.x;
    int lane = tid & 63, wv = tid >> 6;
    if (tid == 0) carry_s = 0;
    for (int base = 0; base < NN; base += 1024) {
        int i = base + tid;
        int v = (i < NN) ? cnt[i] : 0;
        // inclusive wave scan
        int s = v;
#pragma unroll
        for (int off = 1; off < 64; off <<= 1) {
            int t = __shfl_up(s, off, 64);
            if (lane >= off) s += t;
        }
        if (lane == 63) wsum[wv] = s;
        __syncthreads();
        int woff = 0;
        for (int w = 0; w < wv; w++) woff += wsum[w];
        int carry = carry_s;
        if (i < NN) rowp[i] = carry + woff + s - v;   // exclusive
        __syncthreads();
        if (tid == 1023) carry_s = carry + woff + s;  // running total
        __syncthreads();
    }
    if (tid == 0) rowp[NN] = carry_s;
}

__global__ void k_scatter(const int* __restrict__ ei, const float* __restrict__ ew,
                          const float* __restrict__ dinv, const int* __restrict__ rowp,
                          int* __restrict__ fill, int* __restrict__ col,
                          float* __restrict__ val) {
    int e = blockIdx.x * blockDim.x + threadIdx.x;
    if (e >= NE) return;
    int s = ei[e];
    int d = ei[NE + e];
    int pos = rowp[d] + atomicAdd(&fill[d], 1);
    col[pos] = s;
    val[pos] = dinv[s] * ew[e] * dinv[d];
}

// ---------------- input projection: h = relu(x @ W_in + b_in) ----------------
// 256 threads, 64-node tile in LDS, thread = 8 nodes x 4 channels
__global__ __launch_bounds__(256) void k_inproj(const float* __restrict__ x,
                                                const float* __restrict__ W,
                                                const float* __restrict__ b,
                                                float* __restrict__ h) {
    __shared__ float xs[64][IN_CH];          // 16 KB
    int tid = threadIdx.x;
    int cx = tid & 31;                       // channel quad: 4*cx..4*cx+3
    int ny = tid >> 5;                       // 0..7
    int nbase = blockIdx.x * 64;
    const float4* xg = (const float4*)(x + (size_t)nbase * IN_CH);
    float4* xs4 = (float4*)xs;
#pragma unroll
    for (int p = 0; p < 4; p++) {            // 64*16 = 1024 float4s
        int i = p * 256 + tid;
        int row = i >> 4;
        xs4[i] = (nbase + row < NN) ? xg[i] : make_float4(0, 0, 0, 0);
    }
    __syncthreads();
    float4 acc[8];
#pragma unroll
    for (int j = 0; j < 8; j++) acc[j] = make_float4(0, 0, 0, 0);
    const float4* W4 = (const float4*)W;     // W4[k*32 + cx]
#pragma unroll 4
    for (int k4 = 0; k4 < IN_CH / 4; k4++) {
        int k = 4 * k4;
        float4 w0 = W4[(k + 0) * 32 + cx];
        float4 w1 = W4[(k + 1) * 32 + cx];
        float4 w2 = W4[(k + 2) * 32 + cx];
        float4 w3 = W4[(k + 3) * 32 + cx];
#pragma unroll
        for (int j = 0; j < 8; j++) {
            float4 hv = *(const float4*)&xs[ny * 8 + j][k];
            acc[j].x += hv.x * w0.x + hv.y * w1.x + hv.z * w2.x + hv.w * w3.x;
            acc[j].y += hv.x * w0.y + hv.y * w1.y + hv.z * w2.y + hv.w * w3.y;
            acc[j].z += hv.x * w0.z + hv.y * w1.z + hv.z * w2.z + hv.w * w3.z;
            acc[j].w += hv.x * w0.w + hv.y * w1.w + hv.z * w2.w + hv.w * w3.w;
        }
    }
    float4 bc = ((const float4*)b)[cx];
    float4* mg = (float4*)h;
#pragma unroll
    for (int j = 0; j < 8; j++) {
        int n = nbase + ny * 8 + j;
        if (n < NN) {
            float4 o;
            o.x = fmaxf(acc[j].x + bc.x, 0.f);
            o.y = fmaxf(acc[j].y + bc.y, 0.f);
            o.z = fmaxf(acc[j].z + bc.z, 0.f);
            o.w = fmaxf(acc[j].w + bc.w, 0.f);
            mg[n * 32 + cx] = o;
        }
    }
}

// ---------------- per-layer GEMM: m = h @ W_l ----------------
__global__ __launch_bounds__(256) void k_gemm(const float* __restrict__ h,
                                              const float* __restrict__ W,
                                              float* __restrict__ m) {
    __shared__ float hs[64][HID];            // 32 KB
    int tid = threadIdx.x;
    int cx = tid & 31;
    int ny = tid >> 5;
    int nbase = blockIdx.x * 64;
    const float4* hg = (const float4*)(h + (size_t)nbase * HID);
    float4* hs4 = (float4*)hs;
#pragma unroll
    for (int p = 0; p < 8; p++) {            // 64*32 = 2048 float4s
        int i = p * 256 + tid;
        int row = i >> 5;
        hs4[i] = (nbase + row < NN) ? hg[i] : make_float4(0, 0, 0, 0);
    }
    __syncthreads();
    float4 acc[8];
#pragma unroll
    for (int j = 0; j < 8; j++) acc[j] = make_float4(0, 0, 0, 0);
    const float4* W4 = (const float4*)W;
#pragma unroll 4
    for (int k4 = 0; k4 < HID / 4; k4++) {
        int k = 4 * k4;
        float4 w0 = W4[(k + 0) * 32 + cx];
        float4 w1 = W4[(k + 1) * 32 + cx];
        float4 w2 = W4[(k + 2) * 32 + cx];
        float4 w3 = W4[(k + 3) * 32 + cx];
#pragma unroll
        for (int j = 0; j < 8; j++) {
            float4 hv = *(const float4*)&hs[ny * 8 + j][k];
            acc[j].x += hv.x * w0.x + hv.y * w1.x + hv.z * w2.x + hv.w * w3.x;
            acc[j].y += hv.x * w0.y + hv.y * w1.y + hv.z * w2.y + hv.w * w3.y;
            acc[j].z += hv.x * w0.z + hv.y * w1.z + hv.z * w2.z + hv.w * w3.z;
            acc[j].w += hv.x * w0.w + hv.y * w1.w + hv.z * w2.w + hv.w * w3.w;
        }
    }
    float4* mg = (float4*)m;
#pragma unroll
    for (int j = 0; j < 8; j++) {
        int n = nbase + ny * 8 + j;
        if (n < NN) mg[n * 32 + cx] = acc[j];
    }
}

// ---------------- aggregate + bias + LN + relu + residual (in-place h) ----------------
// one wave per node; float2 per lane; no LDS, no __syncthreads
__global__ __launch_bounds__(256) void k_agg(const float* __restrict__ m,
                                             const int* __restrict__ rowp,
                                             const int* __restrict__ col,
                                             const float* __restrict__ val,
                                             const float* __restrict__ dinv,
                                             const float* __restrict__ cb,
                                             const float* __restrict__ g,
                                             const float* __restrict__ bb,
                                             float* __restrict__ h) {
    int lane = threadIdx.x & 63;
    int n = blockIdx.x * 4 + (threadIdx.x >> 6);
    if (n >= NN) return;
    const float2* m2 = (const float2*)m;
    float dn = dinv[n];
    float2 mv = m2[(size_t)n * 64 + lane];
    float2 acc;
    acc.x = dn * dn * mv.x;
    acc.y = dn * dn * mv.y;
    int e0 = rowp[n], e1 = rowp[n + 1];
    for (int e = e0; e < e1; e++) {
        int s = col[e];
        float v = val[e];
        float2 sv = m2[(size_t)s * 64 + lane];
        acc.x += v * sv.x;
        acc.y += v * sv.y;
    }
    float2 cbv = ((const float2*)cb)[lane];
    acc.x += cbv.x;
    acc.y += cbv.y;
    // LayerNorm over 128 channels (whole wave)
    float s1 = acc.x + acc.y;
    float s2 = acc.x * acc.x + acc.y * acc.y;
#pragma unroll
    for (int off = 32; off > 0; off >>= 1) {
        s1 += __shfl_down(s1, off, 64);
        s2 += __shfl_down(s2, off, 64);
    }
    s1 = __shfl(s1, 0, 64);
    s2 = __shfl(s2, 0, 64);
    float mu = s1 * (1.0f / HID);
    float var = s2 * (1.0f / HID) - mu * mu;
    float r = rsqrtf(var + LN_EPS);
    float2 gv = ((const float2*)g)[lane];
    float2 bv = ((const float2*)bb)[lane];
    float2* h2 = (float2*)h;
    float2 hv = h2[(size_t)n * 64 + lane];
    float2 o;
    o.x = fmaxf((acc.x - mu) * r * gv.x + bv.x, 0.f) + hv.x;
    o.y = fmaxf((acc.y - mu) * r * gv.y + bv.y, 0.f) + hv.y;
    h2[(size_t)n * 64 + lane] = o;
}

// ---------------- launch ----------------

extern "C" void kernel_launch(void* const* d_in, const int* in_sizes, int n_in,
                              void* d_out, int out_size, void* d_ws, size_t ws_size,
                              hipStream_t stream) {
    const float* x    = (const float*)d_in[0];
    const int*   ei   = (const int*)d_in[1];
    const float* ew   = (const float*)d_in[2];
    const float* W_in = (const float*)d_in[3];
    const float* b_in = (const float*)d_in[4];
    const float* cW   = (const float*)d_in[5];
    const float* cb   = (const float*)d_in[6];
    const float* lg   = (const float*)d_in[7];
    const float* lb   = (const float*)d_in[8];
    float* h = (float*)d_out;

    char* ws = (char*)d_ws;
    float* deg  = (float*)(ws + 0);        // 50000 f32, becomes dinv in-place
    int*   cnt  = (int*)  (ws + 200192);   // 50000 i32
    int*   fill = (int*)  (ws + 400384);   // 50000 i32
    int*   rowp = (int*)  (ws + 600576);   // 50001 i32
    int*   col  = (int*)  (ws + 800768);   // 800000 i32
    float* val  = (float*)(ws + 4000768);  // 800000 f32
    float* m    = (float*)(ws + 7200768);  // 50000*128 f32

    hipMemsetAsync(d_ws, 0, 600576, stream);

    k_deg_cnt<<<(NE + 255) / 256, 256, 0, stream>>>(ei, ew, deg, cnt);
    k_dinv<<<(NN + 255) / 256, 256, 0, stream>>>(deg);
    k_scan<<<1, 1024, 0, stream>>>(cnt, rowp);
    k_scatter<<<(NE + 255) / 256, 256, 0, stream>>>(ei, ew, deg, rowp, fill, col, val);

    k_inproj<<<(NN + 63) / 64, 256, 0, stream>>>(x, W_in, b_in, h);

    for (int l = 0; l < NL; l++) {
        k_gemm<<<(NN + 63) / 64, 256, 0, stream>>>(h, cW + l * HID * HID, m);
        k_agg<<<(NN + 3) / 4, 256, 0, stream>>>(m, rowp, col, val, deg,
                                                cb + l * HID, lg + l * HID, lb + l * HID, h);
    }
}

// Round 3
// 456.206 us; speedup vs baseline: 2.5416x; 1.5395x over previous
//
#include <hip/hip_runtime.h>
#include <hip/hip_bf16.h>

#define NN 50000
#define NE 800000
#define IN_CH 64
#define HID 128
#define NL 4
#define LN_EPS 1e-5f

// padded CSR capacity: NE + 3*NN < 1,000,000
#define ECAP 1000000

__device__ inline ushort f2bf(float x) {
    __hip_bfloat16 h = __float2bfloat16(x);
    return *(ushort*)&h;
}
__device__ inline float2 bfu(uint u) {
    union { uint i; float f; } a, b;
    a.i = u << 16;
    b.i = u & 0xffff0000u;
    return make_float2(a.f, b.f);
}

// ---------------- preprocessing ----------------

__global__ void k_deg_cnt(const int* __restrict__ ei, const float* __restrict__ ew,
                          float* __restrict__ deg, int* __restrict__ cnt) {
    int e = blockIdx.x * blockDim.x + threadIdx.x;
    if (e >= NE) return;
    int d = ei[NE + e];
    atomicAdd(&deg[d], ew[e]);
    atomicAdd(&cnt[d], 1);
}

__global__ void k_dinv(float* __restrict__ deg) {
    int n = blockIdx.x * blockDim.x + threadIdx.x;
    if (n >= NN) return;
    deg[n] = rsqrtf(deg[n] + 1.0f);
}

// hierarchical scan of padded counts ((cnt+3)&~3) -> rowp (exclusive)
// phase a: per-block (1024) scan -> rowp_tmp (block-exclusive) + bsum[blk]
__global__ __launch_bounds__(1024) void k_scan_a(const int* __restrict__ cnt,
                                                 int* __restrict__ rowp_tmp,
                                                 int* __restrict__ bsum) {
    __shared__ int wsum[16];
    int tid = threadIdx.x;
    int lane = tid & 63, wv = tid >> 6;
    int i = blockIdx.x * 1024 + tid;
    int v = (i < NN) ? ((cnt[i] + 3) & ~3) : 0;
    int s = v;
#pragma unroll
    for (int off = 1; off < 64; off <<= 1) {
        int t = __shfl_up(s, off, 64);
        if (lane >= off) s += t;
    }
    if (lane == 63) wsum[wv] = s;
    __syncthreads();
    int woff = 0;
    for (int w = 0; w < wv; w++) woff += wsum[w];
    if (i < NN) rowp_tmp[i] = woff + s - v;
    if (tid == 1023) bsum[blockIdx.x] = woff + s;
}

// phase b: scan bsum[nb] (nb<=64) in one wave -> boff (exclusive); rowp[NN]=total
__global__ __launch_bounds__(64) void k_scan_b(const int* __restrict__ bsum,
                                               int* __restrict__ boff,
                                               int* __restrict__ rowp, int nb) {
    int t = threadIdx.x;
    int v = (t < nb) ? bsum[t] : 0;
    int s = v;
#pragma unroll
    for (int off = 1; off < 64; off <<= 1) {
        int u = __shfl_up(s, off, 64);
        if (t >= off) s += u;
    }
    if (t < nb) boff[t] = s - v;
    if (t == 63) rowp[NN] = s;
}

// phase c: rowp[i] = rowp_tmp[i] + boff[i>>10]
__global__ __launch_bounds__(1024) void k_scan_c(const int* __restrict__ rowp_tmp,
                                                 const int* __restrict__ boff,
                                                 int* __restrict__ rowp) {
    int i = blockIdx.x * 1024 + threadIdx.x;
    if (i < NN) rowp[i] = rowp_tmp[i] + boff[blockIdx.x];
}

__global__ void k_scatter(const int* __restrict__ ei, const float* __restrict__ ew,
                          const float* __restrict__ dinv, const int* __restrict__ rowp,
                          int* __restrict__ fill, int* __restrict__ col,
                          float* __restrict__ val) {
    int e = blockIdx.x * blockDim.x + threadIdx.x;
    if (e >= NE) return;
    int s = ei[e];
    int d = ei[NE + e];
    int pos = rowp[d] + atomicAdd(&fill[d], 1);
    col[pos] = s;
    val[pos] = dinv[s] * ew[e] * dinv[d];
}

// ---------------- input projection: h = relu(x @ W_in + b_in) ----------------
__global__ __launch_bounds__(256) void k_inproj(const float* __restrict__ x,
                                                const float* __restrict__ W,
                                                const float* __restrict__ b,
                                                float* __restrict__ h) {
    __shared__ float xs[64][IN_CH];
    int tid = threadIdx.x;
    int cx = tid & 31;
    int ny = tid >> 5;
    int nbase = blockIdx.x * 64;
    const float4* xg = (const float4*)(x + (size_t)nbase * IN_CH);
    float4* xs4 = (float4*)xs;
#pragma unroll
    for (int p = 0; p < 4; p++) {
        int i = p * 256 + tid;
        int row = i >> 4;
        xs4[i] = (nbase + row < NN) ? xg[i] : make_float4(0, 0, 0, 0);
    }
    __syncthreads();
    float4 acc[8];
#pragma unroll
    for (int j = 0; j < 8; j++) acc[j] = make_float4(0, 0, 0, 0);
    const float4* W4 = (const float4*)W;
#pragma unroll 4
    for (int k4 = 0; k4 < IN_CH / 4; k4++) {
        int k = 4 * k4;
        float4 w0 = W4[(k + 0) * 32 + cx];
        float4 w1 = W4[(k + 1) * 32 + cx];
        float4 w2 = W4[(k + 2) * 32 + cx];
        float4 w3 = W4[(k + 3) * 32 + cx];
#pragma unroll
        for (int j = 0; j < 8; j++) {
            float4 hv = *(const float4*)&xs[ny * 8 + j][k];
            acc[j].x += hv.x * w0.x + hv.y * w1.x + hv.z * w2.x + hv.w * w3.x;
            acc[j].y += hv.x * w0.y + hv.y * w1.y + hv.z * w2.y + hv.w * w3.y;
            acc[j].z += hv.x * w0.z + hv.y * w1.z + hv.z * w2.z + hv.w * w3.z;
            acc[j].w += hv.x * w0.w + hv.y * w1.w + hv.z * w2.w + hv.w * w3.w;
        }
    }
    float4 bc = ((const float4*)b)[cx];
    float4* mg = (float4*)h;
#pragma unroll
    for (int j = 0; j < 8; j++) {
        int n = nbase + ny * 8 + j;
        if (n < NN) {
            float4 o;
            o.x = fmaxf(acc[j].x + bc.x, 0.f);
            o.y = fmaxf(acc[j].y + bc.y, 0.f);
            o.z = fmaxf(acc[j].z + bc.z, 0.f);
            o.w = fmaxf(acc[j].w + bc.w, 0.f);
            mg[n * 32 + cx] = o;
        }
    }
}

// ---------------- per-layer GEMM: m(bf16) = h(f32) @ W_l ----------------
__global__ __launch_bounds__(256) void k_gemm(const float* __restrict__ h,
                                              const float* __restrict__ W,
                                              ushort* __restrict__ m) {
    __shared__ float hs[64][HID];
    int tid = threadIdx.x;
    int cx = tid & 31;
    int ny = tid >> 5;
    int nbase = blockIdx.x * 64;
    const float4* hg = (const float4*)(h + (size_t)nbase * HID);
    float4* hs4 = (float4*)hs;
#pragma unroll
    for (int p = 0; p < 8; p++) {
        int i = p * 256 + tid;
        int row = i >> 5;
        hs4[i] = (nbase + row < NN) ? hg[i] : make_float4(0, 0, 0, 0);
    }
    __syncthreads();
    float4 acc[8];
#pragma unroll
    for (int j = 0; j < 8; j++) acc[j] = make_float4(0, 0, 0, 0);
    const float4* W4 = (const float4*)W;
#pragma unroll 4
    for (int k4 = 0; k4 < HID / 4; k4++) {
        int k = 4 * k4;
        float4 w0 = W4[(k + 0) * 32 + cx];
        float4 w1 = W4[(k + 1) * 32 + cx];
        float4 w2 = W4[(k + 2) * 32 + cx];
        float4 w3 = W4[(k + 3) * 32 + cx];
#pragma unroll
        for (int j = 0; j < 8; j++) {
            float4 hv = *(const float4*)&hs[ny * 8 + j][k];
            acc[j].x += hv.x * w0.x + hv.y * w1.x + hv.z * w2.x + hv.w * w3.x;
            acc[j].y += hv.x * w0.y + hv.y * w1.y + hv.z * w2.y + hv.w * w3.y;
            acc[j].z += hv.x * w0.z + hv.y * w1.z + hv.z * w2.z + hv.w * w3.z;
            acc[j].w += hv.x * w0.w + hv.y * w1.w + hv.z * w2.w + hv.w * w3.w;
        }
    }
    ushort4* mg = (ushort4*)m;
#pragma unroll
    for (int j = 0; j < 8; j++) {
        int n = nbase + ny * 8 + j;
        if (n < NN) {
            ushort4 o;
            o.x = f2bf(acc[j].x);
            o.y = f2bf(acc[j].y);
            o.z = f2bf(acc[j].z);
            o.w = f2bf(acc[j].w);
            mg[(size_t)n * 32 + cx] = o;
        }
    }
}

// ---------------- aggregate + bias + LN + relu + residual (in-place h) ----------------
// one wave per node; 2 bf16 channels per lane; unroll-4 over padded CSR
__global__ __launch_bounds__(256) void k_agg(const ushort* __restrict__ m,
                                             const int* __restrict__ rowp,
                                             const int* __restrict__ col,
                                             const float* __restrict__ val,
                                             const float* __restrict__ dinv,
                                             const float* __restrict__ cb,
                                             const float* __restrict__ g,
                                             const float* __restrict__ bb,
                                             float* __restrict__ h) {
    int lane = threadIdx.x & 63;
    int n = blockIdx.x * 4 + (threadIdx.x >> 6);
    if (n >= NN) return;
    const uint* m32 = (const uint*)m;
    float dn = dinv[n];
    float2 mv = bfu(m32[(size_t)n * 64 + lane]);
    float2 a0, a1, a2, a3;
    a0.x = dn * dn * mv.x; a0.y = dn * dn * mv.y;
    a1 = make_float2(0, 0); a2 = make_float2(0, 0); a3 = make_float2(0, 0);
    int q0 = rowp[n] >> 2, q1 = rowp[n + 1] >> 2;
    const int4* c4 = (const int4*)col;
    const float4* v4 = (const float4*)val;
    for (int q = q0; q < q1; q++) {
        int4 cc = c4[q];
        float4 vv = v4[q];
        float2 r0 = bfu(m32[(size_t)cc.x * 64 + lane]);
        float2 r1 = bfu(m32[(size_t)cc.y * 64 + lane]);
        float2 r2 = bfu(m32[(size_t)cc.z * 64 + lane]);
        float2 r3 = bfu(m32[(size_t)cc.w * 64 + lane]);
        a0.x += vv.x * r0.x; a0.y += vv.x * r0.y;
        a1.x += vv.y * r1.x; a1.y += vv.y * r1.y;
        a2.x += vv.z * r2.x; a2.y += vv.z * r2.y;
        a3.x += vv.w * r3.x; a3.y += vv.w * r3.y;
    }
    float2 cbv = ((const float2*)cb)[lane];
    float2 acc;
    acc.x = a0.x + a1.x + a2.x + a3.x + cbv.x;
    acc.y = a0.y + a1.y + a2.y + a3.y + cbv.y;
    // LayerNorm over 128 channels (whole wave)
    float s1 = acc.x + acc.y;
    float s2 = acc.x * acc.x + acc.y * acc.y;
#pragma unroll
    for (int off = 32; off > 0; off >>= 1) {
        s1 += __shfl_down(s1, off, 64);
        s2 += __shfl_down(s2, off, 64);
    }
    s1 = __shfl(s1, 0, 64);
    s2 = __shfl(s2, 0, 64);
    float mu = s1 * (1.0f / HID);
    float var = s2 * (1.0f / HID) - mu * mu;
    float r = rsqrtf(var + LN_EPS);
    float2 gv = ((const float2*)g)[lane];
    float2 bv = ((const float2*)bb)[lane];
    float2* h2 = (float2*)h;
    float2 hv = h2[(size_t)n * 64 + lane];
    float2 o;
    o.x = fmaxf((acc.x - mu) * r * gv.x + bv.x, 0.f) + hv.x;
    o.y = fmaxf((acc.y - mu) * r * gv.y + bv.y, 0.f) + hv.y;
    h2[(size_t)n * 64 + lane] = o;
}

// ---------------- launch ----------------

extern "C" void kernel_launch(void* const* d_in, const int* in_sizes, int n_in,
                              void* d_out, int out_size, void* d_ws, size_t ws_size,
                              hipStream_t stream) {
    const float* x    = (const float*)d_in[0];
    const int*   ei   = (const int*)d_in[1];
    const float* ew   = (const float*)d_in[2];
    const float* W_in = (const float*)d_in[3];
    const float* b_in = (const float*)d_in[4];
    const float* cW   = (const float*)d_in[5];
    const float* cb   = (const float*)d_in[6];
    const float* lg   = (const float*)d_in[7];
    const float* lb   = (const float*)d_in[8];
    float* h = (float*)d_out;

    char* ws = (char*)d_ws;
    float*  deg      = (float*)(ws + 0);         // 50000 f32 -> dinv in-place
    int*    cnt      = (int*)  (ws + 200704);
    int*    fill     = (int*)  (ws + 401408);
    int*    rowp     = (int*)  (ws + 602112);    // 50001
    int*    rowp_tmp = (int*)  (ws + 802816);
    int*    bsum     = (int*)  (ws + 1003520);   // 64
    int*    boff     = (int*)  (ws + 1003776);   // 64
    int*    col      = (int*)  (ws + 1004032);   // ECAP i32
    float*  val      = (float*)(ws + 5004032);   // ECAP f32
    ushort* m        = (ushort*)(ws + 9004032);  // 50000*128 bf16

    const int NB = (NN + 1023) / 1024;           // 49

    // zero deg, cnt, fill (contiguous prefix) and col, val (padding slots)
    hipMemsetAsync(ws, 0, 602112, stream);
    hipMemsetAsync(ws + 1004032, 0, (size_t)ECAP * 8, stream);

    k_deg_cnt<<<(NE + 255) / 256, 256, 0, stream>>>(ei, ew, deg, cnt);
    k_dinv<<<(NN + 255) / 256, 256, 0, stream>>>(deg);
    k_scan_a<<<NB, 1024, 0, stream>>>(cnt, rowp_tmp, bsum);
    k_scan_b<<<1, 64, 0, stream>>>(bsum, boff, rowp, NB);
    k_scan_c<<<NB, 1024, 0, stream>>>(rowp_tmp, boff, rowp);
    k_scatter<<<(NE + 255) / 256, 256, 0, stream>>>(ei, ew, deg, rowp, fill, col, val);

    k_inproj<<<(NN + 63) / 64, 256, 0, stream>>>(x, W_in, b_in, h);

    for (int l = 0; l < NL; l++) {
        k_gemm<<<(NN + 63) / 64, 256, 0, stream>>>(h, cW + l * HID * HID, m);
        k_agg<<<(NN + 3) / 4, 256, 0, stream>>>(m, rowp, col, val, deg,
                                                cb + l * HID, lg + l * HID, lb + l * HID, h);
    }
}

// Round 4
// 394.448 us; speedup vs baseline: 2.9395x; 1.1566x over previous
//
#include <hip/hip_runtime.h>
#include <hip/hip_bf16.h>

#define NN 50000
#define NE 800000
#define IN_CH 64
#define HID 128
#define NL 4
#define LN_EPS 1e-5f

// padded CSR capacity: NE + 3*NN < 1,000,000
#define ECAP 1000000
#define WSCALE 1048576.0f   // 2^20 fixed point for edge-weight sums

__device__ inline ushort f2bf(float x) {
    __hip_bfloat16 h = __float2bfloat16(x);
    return *(ushort*)&h;
}
__device__ inline float2 bfu(uint u) {
    union { uint i; float f; } a, b;
    a.i = u << 16;
    b.i = u & 0xffff0000u;
    return make_float2(a.f, b.f);
}

// ---------------- preprocessing ----------------

// one packed 64-bit atomic per edge: hi32 = count, lo32 = Q20 weight sum.
// returns per-destination ordinal via the old count.
__global__ void k_deg_cnt(const int* __restrict__ ei, const float* __restrict__ ew,
                          unsigned long long* __restrict__ pk, int* __restrict__ ord) {
    int e = blockIdx.x * blockDim.x + threadIdx.x;
    if (e >= NE) return;
    int d = ei[NE + e];
    unsigned int wq = (unsigned int)__float2uint_rn(ew[e] * WSCALE);
    unsigned long long old = atomicAdd(&pk[d], (1ULL << 32) | (unsigned long long)wq);
    ord[e] = (int)(old >> 32);
}

__global__ void k_dinv(const unsigned long long* __restrict__ pk,
                       float* __restrict__ dinv) {
    int n = blockIdx.x * blockDim.x + threadIdx.x;
    if (n >= NN) return;
    float deg = (float)(unsigned int)(pk[n] & 0xffffffffu) * (1.0f / WSCALE);
    dinv[n] = rsqrtf(deg + 1.0f);
}

// hierarchical scan of padded counts ((cnt+3)&~3) -> rowp (exclusive)
__global__ __launch_bounds__(1024) void k_scan_a(const unsigned long long* __restrict__ pk,
                                                 int* __restrict__ rowp_tmp,
                                                 int* __restrict__ bsum) {
    __shared__ int wsum[16];
    int tid = threadIdx.x;
    int lane = tid & 63, wv = tid >> 6;
    int i = blockIdx.x * 1024 + tid;
    int v = (i < NN) ? (((int)(pk[i] >> 32) + 3) & ~3) : 0;
    int s = v;
#pragma unroll
    for (int off = 1; off < 64; off <<= 1) {
        int t = __shfl_up(s, off, 64);
        if (lane >= off) s += t;
    }
    if (lane == 63) wsum[wv] = s;
    __syncthreads();
    int woff = 0;
    for (int w = 0; w < wv; w++) woff += wsum[w];
    if (i < NN) rowp_tmp[i] = woff + s - v;
    if (tid == 1023) bsum[blockIdx.x] = woff + s;
}

__global__ __launch_bounds__(64) void k_scan_b(const int* __restrict__ bsum,
                                               int* __restrict__ boff,
                                               int* __restrict__ rowp, int nb) {
    int t = threadIdx.x;
    int v = (t < nb) ? bsum[t] : 0;
    int s = v;
#pragma unroll
    for (int off = 1; off < 64; off <<= 1) {
        int u = __shfl_up(s, off, 64);
        if (t >= off) s += u;
    }
    if (t < nb) boff[t] = s - v;
    if (t == 63) rowp[NN] = s;
}

__global__ __launch_bounds__(1024) void k_scan_c(const int* __restrict__ rowp_tmp,
                                                 const int* __restrict__ boff,
                                                 int* __restrict__ rowp) {
    int i = blockIdx.x * 1024 + threadIdx.x;
    if (i < NN) rowp[i] = rowp_tmp[i] + boff[blockIdx.x];
}

// atomic-free scatter: pos = rowp[d] + ord[e]; one int2 record per edge
__global__ void k_scatter(const int* __restrict__ ei, const float* __restrict__ ew,
                          const float* __restrict__ dinv, const int* __restrict__ rowp,
                          const int* __restrict__ ord, int2* __restrict__ evrec) {
    int e = blockIdx.x * blockDim.x + threadIdx.x;
    if (e >= NE) return;
    int s = ei[e];
    int d = ei[NE + e];
    int pos = rowp[d] + ord[e];
    float v = dinv[s] * ew[e] * dinv[d];
    evrec[pos] = make_int2(s, __float_as_int(v));
}

// ---------------- input projection: h = relu(x @ W_in + b_in) ----------------
__global__ __launch_bounds__(256) void k_inproj(const float* __restrict__ x,
                                                const float* __restrict__ W,
                                                const float* __restrict__ b,
                                                float* __restrict__ h) {
    __shared__ float xs[64][IN_CH];
    int tid = threadIdx.x;
    int cx = tid & 31;
    int ny = tid >> 5;
    int nbase = blockIdx.x * 64;
    const float4* xg = (const float4*)(x + (size_t)nbase * IN_CH);
    float4* xs4 = (float4*)xs;
#pragma unroll
    for (int p = 0; p < 4; p++) {
        int i = p * 256 + tid;
        int row = i >> 4;
        xs4[i] = (nbase + row < NN) ? xg[i] : make_float4(0, 0, 0, 0);
    }
    __syncthreads();
    float4 acc[8];
#pragma unroll
    for (int j = 0; j < 8; j++) acc[j] = make_float4(0, 0, 0, 0);
    const float4* W4 = (const float4*)W;
#pragma unroll 4
    for (int k4 = 0; k4 < IN_CH / 4; k4++) {
        int k = 4 * k4;
        float4 w0 = W4[(k + 0) * 32 + cx];
        float4 w1 = W4[(k + 1) * 32 + cx];
        float4 w2 = W4[(k + 2) * 32 + cx];
        float4 w3 = W4[(k + 3) * 32 + cx];
#pragma unroll
        for (int j = 0; j < 8; j++) {
            float4 hv = *(const float4*)&xs[ny * 8 + j][k];
            acc[j].x += hv.x * w0.x + hv.y * w1.x + hv.z * w2.x + hv.w * w3.x;
            acc[j].y += hv.x * w0.y + hv.y * w1.y + hv.z * w2.y + hv.w * w3.y;
            acc[j].z += hv.x * w0.z + hv.y * w1.z + hv.z * w2.z + hv.w * w3.z;
            acc[j].w += hv.x * w0.w + hv.y * w1.w + hv.z * w2.w + hv.w * w3.w;
        }
    }
    float4 bc = ((const float4*)b)[cx];
    float4* mg = (float4*)h;
#pragma unroll
    for (int j = 0; j < 8; j++) {
        int n = nbase + ny * 8 + j;
        if (n < NN) {
            float4 o;
            o.x = fmaxf(acc[j].x + bc.x, 0.f);
            o.y = fmaxf(acc[j].y + bc.y, 0.f);
            o.z = fmaxf(acc[j].z + bc.z, 0.f);
            o.w = fmaxf(acc[j].w + bc.w, 0.f);
            mg[n * 32 + cx] = o;
        }
    }
}

// ---------------- per-layer GEMM: m(bf16) = h(f32) @ W_l ----------------
__global__ __launch_bounds__(256) void k_gemm(const float* __restrict__ h,
                                              const float* __restrict__ W,
                                              ushort* __restrict__ m) {
    __shared__ float hs[64][HID];
    int tid = threadIdx.x;
    int cx = tid & 31;
    int ny = tid >> 5;
    int nbase = blockIdx.x * 64;
    const float4* hg = (const float4*)(h + (size_t)nbase * HID);
    float4* hs4 = (float4*)hs;
#pragma unroll
    for (int p = 0; p < 8; p++) {
        int i = p * 256 + tid;
        int row = i >> 5;
        hs4[i] = (nbase + row < NN) ? hg[i] : make_float4(0, 0, 0, 0);
    }
    __syncthreads();
    float4 acc[8];
#pragma unroll
    for (int j = 0; j < 8; j++) acc[j] = make_float4(0, 0, 0, 0);
    const float4* W4 = (const float4*)W;
#pragma unroll 4
    for (int k4 = 0; k4 < HID / 4; k4++) {
        int k = 4 * k4;
        float4 w0 = W4[(k + 0) * 32 + cx];
        float4 w1 = W4[(k + 1) * 32 + cx];
        float4 w2 = W4[(k + 2) * 32 + cx];
        float4 w3 = W4[(k + 3) * 32 + cx];
#pragma unroll
        for (int j = 0; j < 8; j++) {
            float4 hv = *(const float4*)&hs[ny * 8 + j][k];
            acc[j].x += hv.x * w0.x + hv.y * w1.x + hv.z * w2.x + hv.w * w3.x;
            acc[j].y += hv.x * w0.y + hv.y * w1.y + hv.z * w2.y + hv.w * w3.y;
            acc[j].z += hv.x * w0.z + hv.y * w1.z + hv.z * w2.z + hv.w * w3.z;
            acc[j].w += hv.x * w0.w + hv.y * w1.w + hv.z * w2.w + hv.w * w3.w;
        }
    }
    ushort4* mg = (ushort4*)m;
#pragma unroll
    for (int j = 0; j < 8; j++) {
        int n = nbase + ny * 8 + j;
        if (n < NN) {
            ushort4 o;
            o.x = f2bf(acc[j].x);
            o.y = f2bf(acc[j].y);
            o.z = f2bf(acc[j].z);
            o.w = f2bf(acc[j].w);
            mg[(size_t)n * 32 + cx] = o;
        }
    }
}

// ---------------- aggregate + bias + LN + relu + residual (in-place h) ----------------
__global__ __launch_bounds__(256) void k_agg(const ushort* __restrict__ m,
                                             const int* __restrict__ rowp,
                                             const int2* __restrict__ evrec,
                                             const float* __restrict__ dinv,
                                             const float* __restrict__ cb,
                                             const float* __restrict__ g,
                                             const float* __restrict__ bb,
                                             float* __restrict__ h) {
    int lane = threadIdx.x & 63;
    int n = blockIdx.x * 4 + (threadIdx.x >> 6);
    if (n >= NN) return;
    const uint* m32 = (const uint*)m;
    float dn = dinv[n];
    float2 mv = bfu(m32[(size_t)n * 64 + lane]);
    float2 a0, a1, a2, a3;
    a0.x = dn * dn * mv.x; a0.y = dn * dn * mv.y;
    a1 = make_float2(0, 0); a2 = make_float2(0, 0); a3 = make_float2(0, 0);
    int r0 = rowp[n], r1 = rowp[n + 1];          // multiples of 4
    const int4* e4 = (const int4*)evrec;
    for (int r = r0; r < r1; r += 4) {
        int4 p0 = e4[r >> 1];
        int4 p1 = e4[(r >> 1) + 1];
        float2 g0 = bfu(m32[(size_t)p0.x * 64 + lane]);
        float2 g1 = bfu(m32[(size_t)p0.z * 64 + lane]);
        float2 g2 = bfu(m32[(size_t)p1.x * 64 + lane]);
        float2 g3 = bfu(m32[(size_t)p1.z * 64 + lane]);
        float v0 = __int_as_float(p0.y), v1 = __int_as_float(p0.w);
        float v2 = __int_as_float(p1.y), v3 = __int_as_float(p1.w);
        a0.x += v0 * g0.x; a0.y += v0 * g0.y;
        a1.x += v1 * g1.x; a1.y += v1 * g1.y;
        a2.x += v2 * g2.x; a2.y += v2 * g2.y;
        a3.x += v3 * g3.x; a3.y += v3 * g3.y;
    }
    float2 cbv = ((const float2*)cb)[lane];
    float2 acc;
    acc.x = a0.x + a1.x + a2.x + a3.x + cbv.x;
    acc.y = a0.y + a1.y + a2.y + a3.y + cbv.y;
    float s1 = acc.x + acc.y;
    float s2 = acc.x * acc.x + acc.y * acc.y;
#pragma unroll
    for (int off = 32; off > 0; off >>= 1) {
        s1 += __shfl_down(s1, off, 64);
        s2 += __shfl_down(s2, off, 64);
    }
    s1 = __shfl(s1, 0, 64);
    s2 = __shfl(s2, 0, 64);
    float mu = s1 * (1.0f / HID);
    float var = s2 * (1.0f / HID) - mu * mu;
    float r = rsqrtf(var + LN_EPS);
    float2 gv = ((const float2*)g)[lane];
    float2 bv = ((const float2*)bb)[lane];
    float2* h2 = (float2*)h;
    float2 hv = h2[(size_t)n * 64 + lane];
    float2 o;
    o.x = fmaxf((acc.x - mu) * r * gv.x + bv.x, 0.f) + hv.x;
    o.y = fmaxf((acc.y - mu) * r * gv.y + bv.y, 0.f) + hv.y;
    h2[(size_t)n * 64 + lane] = o;
}

// ---------------- launch ----------------

extern "C" void kernel_launch(void* const* d_in, const int* in_sizes, int n_in,
                              void* d_out, int out_size, void* d_ws, size_t ws_size,
                              hipStream_t stream) {
    const float* x    = (const float*)d_in[0];
    const int*   ei   = (const int*)d_in[1];
    const float* ew   = (const float*)d_in[2];
    const float* W_in = (const float*)d_in[3];
    const float* b_in = (const float*)d_in[4];
    const float* cW   = (const float*)d_in[5];
    const float* cb   = (const float*)d_in[6];
    const float* lg   = (const float*)d_in[7];
    const float* lb   = (const float*)d_in[8];
    float* h = (float*)d_out;

    char* ws = (char*)d_ws;
    unsigned long long* pk = (unsigned long long*)(ws + 0);   // 50000 u64 (cnt|Q20 deg)
    int*    rowp     = (int*)  (ws + 401408);                 // 50001
    int*    rowp_tmp = (int*)  (ws + 602112);
    int*    bsum     = (int*)  (ws + 802816);                 // 64
    int*    boff     = (int*)  (ws + 803072);                 // 64
    int2*   evrec    = (int2*) (ws + 803328);                 // ECAP int2 (8 MB)
    ushort* m        = (ushort*)(ws + 8803328);               // 50000*128 bf16 (12.8 MB)
    int*    ord      = (int*)  (ws + 8803328);                // aliases m (dead until gemm)
    float*  dinv     = (float*)(ws + 21603328);               // 50000 f32

    const int NB = (NN + 1023) / 1024;                        // 49

    hipMemsetAsync(ws, 0, 401408, stream);                    // pk
    hipMemsetAsync(ws + 803328, 0, (size_t)ECAP * 8, stream); // evrec padding

    k_deg_cnt<<<(NE + 255) / 256, 256, 0, stream>>>(ei, ew, pk, ord);
    k_dinv<<<(NN + 255) / 256, 256, 0, stream>>>(pk, dinv);
    k_scan_a<<<NB, 1024, 0, stream>>>(pk, rowp_tmp, bsum);
    k_scan_b<<<1, 64, 0, stream>>>(bsum, boff, rowp, NB);
    k_scan_c<<<NB, 1024, 0, stream>>>(rowp_tmp, boff, rowp);
    k_scatter<<<(NE + 255) / 256, 256, 0, stream>>>(ei, ew, dinv, rowp, ord, evrec);

    k_inproj<<<(NN + 63) / 64, 256, 0, stream>>>(x, W_in, b_in, h);

    for (int l = 0; l < NL; l++) {
        k_gemm<<<(NN + 63) / 64, 256, 0, stream>>>(h, cW + l * HID * HID, m);
        k_agg<<<(NN + 3) / 4, 256, 0, stream>>>(m, rowp, evrec, dinv,
                                                cb + l * HID, lg + l * HID, lb + l * HID, h);
    }
}

// Round 5
// 391.393 us; speedup vs baseline: 2.9624x; 1.0078x over previous
//
#include <hip/hip_runtime.h>
#include <hip/hip_bf16.h>

#define NN 50000
#define NE 800000
#define IN_CH 64
#define HID 128
#define NL 4
#define LN_EPS 1e-5f

// padded CSR capacity: NE + 3*NN < 1,000,000
#define ECAP 1000000
#define WSCALE 1048576.0f   // 2^20 fixed point for edge-weight sums

__device__ inline ushort f2bf(float x) {
    __hip_bfloat16 h = __float2bfloat16(x);
    return *(ushort*)&h;
}
__device__ inline float2 bfu(uint u) {
    union { uint i; float f; } a, b;
    a.i = u << 16;
    b.i = u & 0xffff0000u;
    return make_float2(a.f, b.f);
}

// ---------------- preprocessing ----------------

// zero pk (50000 u64 = 100000 i32) with int4 stores
__global__ void k_zero(int4* __restrict__ p, int n4) {
    int i = blockIdx.x * blockDim.x + threadIdx.x;
    if (i < n4) p[i] = make_int4(0, 0, 0, 0);
}

// one packed 64-bit atomic per edge: hi32 = count, lo32 = Q20 weight sum.
__global__ void k_deg_cnt(const int* __restrict__ ei, const float* __restrict__ ew,
                          unsigned long long* __restrict__ pk, int* __restrict__ ord) {
    int e = blockIdx.x * blockDim.x + threadIdx.x;
    if (e >= NE) return;
    int d = ei[NE + e];
    unsigned int wq = (unsigned int)__float2uint_rn(ew[e] * WSCALE);
    unsigned long long old = atomicAdd(&pk[d], (1ULL << 32) | (unsigned long long)wq);
    ord[e] = (int)(old >> 32);
}

__global__ void k_dinv(const unsigned long long* __restrict__ pk,
                       float* __restrict__ dinv) {
    int n = blockIdx.x * blockDim.x + threadIdx.x;
    if (n >= NN) return;
    float deg = (float)(unsigned int)(pk[n] & 0xffffffffu) * (1.0f / WSCALE);
    dinv[n] = rsqrtf(deg + 1.0f);
}

// hierarchical scan of padded counts ((cnt+3)&~3) -> rowp (exclusive)
__global__ __launch_bounds__(1024) void k_scan_a(const unsigned long long* __restrict__ pk,
                                                 int* __restrict__ rowp_tmp,
                                                 int* __restrict__ bsum) {
    __shared__ int wsum[16];
    int tid = threadIdx.x;
    int lane = tid & 63, wv = tid >> 6;
    int i = blockIdx.x * 1024 + tid;
    int v = (i < NN) ? (((int)(pk[i] >> 32) + 3) & ~3) : 0;
    int s = v;
#pragma unroll
    for (int off = 1; off < 64; off <<= 1) {
        int t = __shfl_up(s, off, 64);
        if (lane >= off) s += t;
    }
    if (lane == 63) wsum[wv] = s;
    __syncthreads();
    int woff = 0;
    for (int w = 0; w < wv; w++) woff += wsum[w];
    if (i < NN) rowp_tmp[i] = woff + s - v;
    if (tid == 1023) bsum[blockIdx.x] = woff + s;
}

__global__ __launch_bounds__(64) void k_scan_b(const int* __restrict__ bsum,
                                               int* __restrict__ boff,
                                               int* __restrict__ rowp, int nb) {
    int t = threadIdx.x;
    int v = (t < nb) ? bsum[t] : 0;
    int s = v;
#pragma unroll
    for (int off = 1; off < 64; off <<= 1) {
        int u = __shfl_up(s, off, 64);
        if (t >= off) s += u;
    }
    if (t < nb) boff[t] = s - v;
    if (t == 63) rowp[NN] = s;
}

__global__ __launch_bounds__(1024) void k_scan_c(const int* __restrict__ rowp_tmp,
                                                 const int* __restrict__ boff,
                                                 int* __restrict__ rowp) {
    int i = blockIdx.x * 1024 + threadIdx.x;
    if (i < NN) rowp[i] = rowp_tmp[i] + boff[blockIdx.x];
}

// zero only the padding slots: [rowp[n] + cnt[n], rowp[n+1])
__global__ void k_pad(const unsigned long long* __restrict__ pk,
                      const int* __restrict__ rowp, int2* __restrict__ evrec) {
    int n = blockIdx.x * blockDim.x + threadIdx.x;
    if (n >= NN) return;
    int cnt = (int)(pk[n] >> 32);
    int p0 = rowp[n] + cnt, p1 = rowp[n + 1];
    for (int p = p0; p < p1; p++) evrec[p] = make_int2(0, 0);
}

// atomic-free scatter: pos = rowp[d] + ord[e]; one int2 record per edge
__global__ void k_scatter(const int* __restrict__ ei, const float* __restrict__ ew,
                          const float* __restrict__ dinv, const int* __restrict__ rowp,
                          const int* __restrict__ ord, int2* __restrict__ evrec) {
    int e = blockIdx.x * blockDim.x + threadIdx.x;
    if (e >= NE) return;
    int s = ei[e];
    int d = ei[NE + e];
    int pos = rowp[d] + ord[e];
    float v = dinv[s] * ew[e] * dinv[d];
    evrec[pos] = make_int2(s, __float_as_int(v));
}

// ---------------- input projection: h = relu(x @ W_in + b_in) ----------------
__global__ __launch_bounds__(256) void k_inproj(const float* __restrict__ x,
                                                const float* __restrict__ W,
                                                const float* __restrict__ b,
                                                float* __restrict__ h) {
    __shared__ float xs[64][IN_CH];
    int tid = threadIdx.x;
    int cx = tid & 31;
    int ny = tid >> 5;
    int nbase = blockIdx.x * 64;
    const float4* xg = (const float4*)(x + (size_t)nbase * IN_CH);
    float4* xs4 = (float4*)xs;
#pragma unroll
    for (int p = 0; p < 4; p++) {
        int i = p * 256 + tid;
        int row = i >> 4;
        xs4[i] = (nbase + row < NN) ? xg[i] : make_float4(0, 0, 0, 0);
    }
    __syncthreads();
    float4 acc[8];
#pragma unroll
    for (int j = 0; j < 8; j++) acc[j] = make_float4(0, 0, 0, 0);
    const float4* W4 = (const float4*)W;
#pragma unroll 4
    for (int k4 = 0; k4 < IN_CH / 4; k4++) {
        int k = 4 * k4;
        float4 w0 = W4[(k + 0) * 32 + cx];
        float4 w1 = W4[(k + 1) * 32 + cx];
        float4 w2 = W4[(k + 2) * 32 + cx];
        float4 w3 = W4[(k + 3) * 32 + cx];
#pragma unroll
        for (int j = 0; j < 8; j++) {
            float4 hv = *(const float4*)&xs[ny * 8 + j][k];
            acc[j].x += hv.x * w0.x + hv.y * w1.x + hv.z * w2.x + hv.w * w3.x;
            acc[j].y += hv.x * w0.y + hv.y * w1.y + hv.z * w2.y + hv.w * w3.y;
            acc[j].z += hv.x * w0.z + hv.y * w1.z + hv.z * w2.z + hv.w * w3.z;
            acc[j].w += hv.x * w0.w + hv.y * w1.w + hv.z * w2.w + hv.w * w3.w;
        }
    }
    float4 bc = ((const float4*)b)[cx];
    float4* mg = (float4*)h;
#pragma unroll
    for (int j = 0; j < 8; j++) {
        int n = nbase + ny * 8 + j;
        if (n < NN) {
            float4 o;
            o.x = fmaxf(acc[j].x + bc.x, 0.f);
            o.y = fmaxf(acc[j].y + bc.y, 0.f);
            o.z = fmaxf(acc[j].z + bc.z, 0.f);
            o.w = fmaxf(acc[j].w + bc.w, 0.f);
            mg[n * 32 + cx] = o;
        }
    }
}

// ---------------- per-layer GEMM: m(bf16) = h(f32) @ W_l ----------------
__global__ __launch_bounds__(256) void k_gemm(const float* __restrict__ h,
                                              const float* __restrict__ W,
                                              ushort* __restrict__ m) {
    __shared__ float hs[64][HID];
    int tid = threadIdx.x;
    int cx = tid & 31;
    int ny = tid >> 5;
    int nbase = blockIdx.x * 64;
    const float4* hg = (const float4*)(h + (size_t)nbase * HID);
    float4* hs4 = (float4*)hs;
#pragma unroll
    for (int p = 0; p < 8; p++) {
        int i = p * 256 + tid;
        int row = i >> 5;
        hs4[i] = (nbase + row < NN) ? hg[i] : make_float4(0, 0, 0, 0);
    }
    __syncthreads();
    float4 acc[8];
#pragma unroll
    for (int j = 0; j < 8; j++) acc[j] = make_float4(0, 0, 0, 0);
    const float4* W4 = (const float4*)W;
#pragma unroll 4
    for (int k4 = 0; k4 < HID / 4; k4++) {
        int k = 4 * k4;
        float4 w0 = W4[(k + 0) * 32 + cx];
        float4 w1 = W4[(k + 1) * 32 + cx];
        float4 w2 = W4[(k + 2) * 32 + cx];
        float4 w3 = W4[(k + 3) * 32 + cx];
#pragma unroll
        for (int j = 0; j < 8; j++) {
            float4 hv = *(const float4*)&hs[ny * 8 + j][k];
            acc[j].x += hv.x * w0.x + hv.y * w1.x + hv.z * w2.x + hv.w * w3.x;
            acc[j].y += hv.x * w0.y + hv.y * w1.y + hv.z * w2.y + hv.w * w3.y;
            acc[j].z += hv.x * w0.z + hv.y * w1.z + hv.z * w2.z + hv.w * w3.z;
            acc[j].w += hv.x * w0.w + hv.y * w1.w + hv.z * w2.w + hv.w * w3.w;
        }
    }
    ushort4* mg = (ushort4*)m;
#pragma unroll
    for (int j = 0; j < 8; j++) {
        int n = nbase + ny * 8 + j;
        if (n < NN) {
            ushort4 o;
            o.x = f2bf(acc[j].x);
            o.y = f2bf(acc[j].y);
            o.z = f2bf(acc[j].z);
            o.w = f2bf(acc[j].w);
            mg[(size_t)n * 32 + cx] = o;
        }
    }
}

// ---------------- aggregate + bias + LN + relu + residual (in-place h) ----------------
__global__ __launch_bounds__(256) void k_agg(const ushort* __restrict__ m,
                                             const int* __restrict__ rowp,
                                             const int2* __restrict__ evrec,
                                             const float* __restrict__ dinv,
                                             const float* __restrict__ cb,
                                             const float* __restrict__ g,
                                             const float* __restrict__ bb,
                                             float* __restrict__ h) {
    int lane = threadIdx.x & 63;
    int n = blockIdx.x * 4 + (threadIdx.x >> 6);
    if (n >= NN) return;
    const uint* m32 = (const uint*)m;
    float dn = dinv[n];
    float2 mv = bfu(m32[(size_t)n * 64 + lane]);
    float2 a0, a1, a2, a3;
    a0.x = dn * dn * mv.x; a0.y = dn * dn * mv.y;
    a1 = make_float2(0, 0); a2 = make_float2(0, 0); a3 = make_float2(0, 0);
    int r0 = rowp[n], r1 = rowp[n + 1];          // multiples of 4
    const int4* e4 = (const int4*)evrec;
    for (int r = r0; r < r1; r += 4) {
        int4 p0 = e4[r >> 1];
        int4 p1 = e4[(r >> 1) + 1];
        float2 g0 = bfu(m32[(size_t)p0.x * 64 + lane]);
        float2 g1 = bfu(m32[(size_t)p0.z * 64 + lane]);
        float2 g2 = bfu(m32[(size_t)p1.x * 64 + lane]);
        float2 g3 = bfu(m32[(size_t)p1.z * 64 + lane]);
        float v0 = __int_as_float(p0.y), v1 = __int_as_float(p0.w);
        float v2 = __int_as_float(p1.y), v3 = __int_as_float(p1.w);
        a0.x += v0 * g0.x; a0.y += v0 * g0.y;
        a1.x += v1 * g1.x; a1.y += v1 * g1.y;
        a2.x += v2 * g2.x; a2.y += v2 * g2.y;
        a3.x += v3 * g3.x; a3.y += v3 * g3.y;
    }
    float2 cbv = ((const float2*)cb)[lane];
    float2 acc;
    acc.x = a0.x + a1.x + a2.x + a3.x + cbv.x;
    acc.y = a0.y + a1.y + a2.y + a3.y + cbv.y;
    float s1 = acc.x + acc.y;
    float s2 = acc.x * acc.x + acc.y * acc.y;
#pragma unroll
    for (int off = 32; off > 0; off >>= 1) {
        s1 += __shfl_down(s1, off, 64);
        s2 += __shfl_down(s2, off, 64);
    }
    s1 = __shfl(s1, 0, 64);
    s2 = __shfl(s2, 0, 64);
    float mu = s1 * (1.0f / HID);
    float var = s2 * (1.0f / HID) - mu * mu;
    float r = rsqrtf(var + LN_EPS);
    float2 gv = ((const float2*)g)[lane];
    float2 bv = ((const float2*)bb)[lane];
    float2* h2 = (float2*)h;
    float2 hv = h2[(size_t)n * 64 + lane];
    float2 o;
    o.x = fmaxf((acc.x - mu) * r * gv.x + bv.x, 0.f) + hv.x;
    o.y = fmaxf((acc.y - mu) * r * gv.y + bv.y, 0.f) + hv.y;
    h2[(size_t)n * 64 + lane] = o;
}

// ---------------- launch ----------------

extern "C" void kernel_launch(void* const* d_in, const int* in_sizes, int n_in,
                              void* d_out, int out_size, void* d_ws, size_t ws_size,
                              hipStream_t stream) {
    const float* x    = (const float*)d_in[0];
    const int*   ei   = (const int*)d_in[1];
    const float* ew   = (const float*)d_in[2];
    const float* W_in = (const float*)d_in[3];
    const float* b_in = (const float*)d_in[4];
    const float* cW   = (const float*)d_in[5];
    const float* cb   = (const float*)d_in[6];
    const float* lg   = (const float*)d_in[7];
    const float* lb   = (const float*)d_in[8];
    float* h = (float*)d_out;

    char* ws = (char*)d_ws;
    unsigned long long* pk = (unsigned long long*)(ws + 0);   // 50000 u64 (cnt|Q20 deg)
    int*    rowp     = (int*)  (ws + 401408);                 // 50001
    int*    rowp_tmp = (int*)  (ws + 602112);
    int*    bsum     = (int*)  (ws + 802816);                 // 64
    int*    boff     = (int*)  (ws + 803072);                 // 64
    int2*   evrec    = (int2*) (ws + 803328);                 // ECAP int2 (8 MB)
    ushort* m        = (ushort*)(ws + 8803328);               // 50000*128 bf16 (12.8 MB)
    int*    ord      = (int*)  (ws + 8803328);                // aliases m (dead until gemm)
    float*  dinv     = (float*)(ws + 21603328);               // 50000 f32

    const int NB = (NN + 1023) / 1024;                        // 49

    k_zero<<<(100000 / 4 + 255) / 256, 256, 0, stream>>>((int4*)pk, 100000 / 4);
    k_deg_cnt<<<(NE + 255) / 256, 256, 0, stream>>>(ei, ew, pk, ord);
    k_dinv<<<(NN + 255) / 256, 256, 0, stream>>>(pk, dinv);
    k_scan_a<<<NB, 1024, 0, stream>>>(pk, rowp_tmp, bsum);
    k_scan_b<<<1, 64, 0, stream>>>(bsum, boff, rowp, NB);
    k_scan_c<<<NB, 1024, 0, stream>>>(rowp_tmp, boff, rowp);
    k_pad<<<(NN + 255) / 256, 256, 0, stream>>>(pk, rowp, evrec);
    k_scatter<<<(NE + 255) / 256, 256, 0, stream>>>(ei, ew, dinv, rowp, ord, evrec);

    k_inproj<<<(NN + 63) / 64, 256, 0, stream>>>(x, W_in, b_in, h);

    for (int l = 0; l < NL; l++) {
        k_gemm<<<(NN + 63) / 64, 256, 0, stream>>>(h, cW + l * HID * HID, m);
        k_agg<<<(NN + 3) / 4, 256, 0, stream>>>(m, rowp, evrec, dinv,
                                                cb + l * HID, lg + l * HID, lb + l * HID, h);
    }
}

// Round 6
// 390.231 us; speedup vs baseline: 2.9713x; 1.0030x over previous
//
#include <hip/hip_runtime.h>
#include <hip/hip_bf16.h>

#define NN 50000
#define NE 800000
#define IN_CH 64
#define HID 128
#define NL 4
#define LN_EPS 1e-5f

// padded CSR capacity: NE + 7*NN = 1,150,000
#define ECAP 1150000
#define WSCALE 1048576.0f   // 2^20 fixed point for edge-weight sums

__device__ inline ushort f2bf(float x) {
    __hip_bfloat16 h = __float2bfloat16(x);
    return *(ushort*)&h;
}
__device__ inline float2 bfu(uint u) {
    union { uint i; float f; } a, b;
    a.i = u << 16;
    b.i = u & 0xffff0000u;
    return make_float2(a.f, b.f);
}
__device__ inline float4 bfu2(uint2 u) {
    float2 lo = bfu(u.x), hi = bfu(u.y);
    return make_float4(lo.x, lo.y, hi.x, hi.y);
}

// ---------------- preprocessing ----------------

__global__ void k_zero(int4* __restrict__ p, int n4) {
    int i = blockIdx.x * blockDim.x + threadIdx.x;
    if (i < n4) p[i] = make_int4(0, 0, 0, 0);
}

// one packed 64-bit atomic per edge: hi32 = count, lo32 = Q20 weight sum.
__global__ void k_deg_cnt(const int* __restrict__ ei, const float* __restrict__ ew,
                          unsigned long long* __restrict__ pk, int* __restrict__ ord) {
    int e = blockIdx.x * blockDim.x + threadIdx.x;
    if (e >= NE) return;
    int d = ei[NE + e];
    unsigned int wq = (unsigned int)__float2uint_rn(ew[e] * WSCALE);
    unsigned long long old = atomicAdd(&pk[d], (1ULL << 32) | (unsigned long long)wq);
    ord[e] = (int)(old >> 32);
}

__global__ void k_dinv(const unsigned long long* __restrict__ pk,
                       float* __restrict__ dinv) {
    int n = blockIdx.x * blockDim.x + threadIdx.x;
    if (n >= NN) return;
    float deg = (float)(unsigned int)(pk[n] & 0xffffffffu) * (1.0f / WSCALE);
    dinv[n] = rsqrtf(deg + 1.0f);
}

// hierarchical scan of padded counts ((cnt+7)&~7) -> rowp (exclusive)
__global__ __launch_bounds__(1024) void k_scan_a(const unsigned long long* __restrict__ pk,
                                                 int* __restrict__ rowp_tmp,
                                                 int* __restrict__ bsum) {
    __shared__ int wsum[16];
    int tid = threadIdx.x;
    int lane = tid & 63, wv = tid >> 6;
    int i = blockIdx.x * 1024 + tid;
    int v = (i < NN) ? (((int)(pk[i] >> 32) + 7) & ~7) : 0;
    int s = v;
#pragma unroll
    for (int off = 1; off < 64; off <<= 1) {
        int t = __shfl_up(s, off, 64);
        if (lane >= off) s += t;
    }
    if (lane == 63) wsum[wv] = s;
    __syncthreads();
    int woff = 0;
    for (int w = 0; w < wv; w++) woff += wsum[w];
    if (i < NN) rowp_tmp[i] = woff + s - v;
    if (tid == 1023) bsum[blockIdx.x] = woff + s;
}

__global__ __launch_bounds__(64) void k_scan_b(const int* __restrict__ bsum,
                                               int* __restrict__ boff,
                                               int* __restrict__ rowp, int nb) {
    int t = threadIdx.x;
    int v = (t < nb) ? bsum[t] : 0;
    int s = v;
#pragma unroll
    for (int off = 1; off < 64; off <<= 1) {
        int u = __shfl_up(s, off, 64);
        if (t >= off) s += u;
    }
    if (t < nb) boff[t] = s - v;
    if (t == 63) rowp[NN] = s;
}

__global__ __launch_bounds__(1024) void k_scan_c(const int* __restrict__ rowp_tmp,
                                                 const int* __restrict__ boff,
                                                 int* __restrict__ rowp) {
    int i = blockIdx.x * 1024 + threadIdx.x;
    if (i < NN) rowp[i] = rowp_tmp[i] + boff[blockIdx.x];
}

// zero only the padding slots: [rowp[n] + cnt[n], rowp[n+1])
__global__ void k_pad(const unsigned long long* __restrict__ pk,
                      const int* __restrict__ rowp, int2* __restrict__ evrec) {
    int n = blockIdx.x * blockDim.x + threadIdx.x;
    if (n >= NN) return;
    int cnt = (int)(pk[n] >> 32);
    int p0 = rowp[n] + cnt, p1 = rowp[n + 1];
    for (int p = p0; p < p1; p++) evrec[p] = make_int2(0, 0);
}

// atomic-free scatter: pos = rowp[d] + ord[e]; one int2 record per edge
__global__ void k_scatter(const int* __restrict__ ei, const float* __restrict__ ew,
                          const float* __restrict__ dinv, const int* __restrict__ rowp,
                          const int* __restrict__ ord, int2* __restrict__ evrec) {
    int e = blockIdx.x * blockDim.x + threadIdx.x;
    if (e >= NE) return;
    int s = ei[e];
    int d = ei[NE + e];
    int pos = rowp[d] + ord[e];
    float v = dinv[s] * ew[e] * dinv[d];
    evrec[pos] = make_int2(s, __float_as_int(v));
}

// ---------------- input projection: h = relu(x @ W_in + b_in) ----------------
__global__ __launch_bounds__(256) void k_inproj(const float* __restrict__ x,
                                                const float* __restrict__ W,
                                                const float* __restrict__ b,
                                                float* __restrict__ h) {
    __shared__ float xs[64][IN_CH];
    int tid = threadIdx.x;
    int cx = tid & 31;
    int ny = tid >> 5;
    int nbase = blockIdx.x * 64;
    const float4* xg = (const float4*)(x + (size_t)nbase * IN_CH);
    float4* xs4 = (float4*)xs;
#pragma unroll
    for (int p = 0; p < 4; p++) {
        int i = p * 256 + tid;
        int row = i >> 4;
        xs4[i] = (nbase + row < NN) ? xg[i] : make_float4(0, 0, 0, 0);
    }
    __syncthreads();
    float4 acc[8];
#pragma unroll
    for (int j = 0; j < 8; j++) acc[j] = make_float4(0, 0, 0, 0);
    const float4* W4 = (const float4*)W;
#pragma unroll 4
    for (int k4 = 0; k4 < IN_CH / 4; k4++) {
        int k = 4 * k4;
        float4 w0 = W4[(k + 0) * 32 + cx];
        float4 w1 = W4[(k + 1) * 32 + cx];
        float4 w2 = W4[(k + 2) * 32 + cx];
        float4 w3 = W4[(k + 3) * 32 + cx];
#pragma unroll
        for (int j = 0; j < 8; j++) {
            float4 hv = *(const float4*)&xs[ny * 8 + j][k];
            acc[j].x += hv.x * w0.x + hv.y * w1.x + hv.z * w2.x + hv.w * w3.x;
            acc[j].y += hv.x * w0.y + hv.y * w1.y + hv.z * w2.y + hv.w * w3.y;
            acc[j].z += hv.x * w0.z + hv.y * w1.z + hv.z * w2.z + hv.w * w3.z;
            acc[j].w += hv.x * w0.w + hv.y * w1.w + hv.z * w2.w + hv.w * w3.w;
        }
    }
    float4 bc = ((const float4*)b)[cx];
    float4* mg = (float4*)h;
#pragma unroll
    for (int j = 0; j < 8; j++) {
        int n = nbase + ny * 8 + j;
        if (n < NN) {
            float4 o;
            o.x = fmaxf(acc[j].x + bc.x, 0.f);
            o.y = fmaxf(acc[j].y + bc.y, 0.f);
            o.z = fmaxf(acc[j].z + bc.z, 0.f);
            o.w = fmaxf(acc[j].w + bc.w, 0.f);
            mg[n * 32 + cx] = o;
        }
    }
}

// ---------------- per-layer GEMM: m(bf16) = h(f32) @ W_l ----------------
__global__ __launch_bounds__(256) void k_gemm(const float* __restrict__ h,
                                              const float* __restrict__ W,
                                              ushort* __restrict__ m) {
    __shared__ float hs[64][HID];
    int tid = threadIdx.x;
    int cx = tid & 31;
    int ny = tid >> 5;
    int nbase = blockIdx.x * 64;
    const float4* hg = (const float4*)(h + (size_t)nbase * HID);
    float4* hs4 = (float4*)hs;
#pragma unroll
    for (int p = 0; p < 8; p++) {
        int i = p * 256 + tid;
        int row = i >> 5;
        hs4[i] = (nbase + row < NN) ? hg[i] : make_float4(0, 0, 0, 0);
    }
    __syncthreads();
    float4 acc[8];
#pragma unroll
    for (int j = 0; j < 8; j++) acc[j] = make_float4(0, 0, 0, 0);
    const float4* W4 = (const float4*)W;
#pragma unroll 4
    for (int k4 = 0; k4 < HID / 4; k4++) {
        int k = 4 * k4;
        float4 w0 = W4[(k + 0) * 32 + cx];
        float4 w1 = W4[(k + 1) * 32 + cx];
        float4 w2 = W4[(k + 2) * 32 + cx];
        float4 w3 = W4[(k + 3) * 32 + cx];
#pragma unroll
        for (int j = 0; j < 8; j++) {
            float4 hv = *(const float4*)&hs[ny * 8 + j][k];
            acc[j].x += hv.x * w0.x + hv.y * w1.x + hv.z * w2.x + hv.w * w3.x;
            acc[j].y += hv.x * w0.y + hv.y * w1.y + hv.z * w2.y + hv.w * w3.y;
            acc[j].z += hv.x * w0.z + hv.y * w1.z + hv.z * w2.z + hv.w * w3.z;
            acc[j].w += hv.x * w0.w + hv.y * w1.w + hv.z * w2.w + hv.w * w3.w;
        }
    }
    ushort4* mg = (ushort4*)m;
#pragma unroll
    for (int j = 0; j < 8; j++) {
        int n = nbase + ny * 8 + j;
        if (n < NN) {
            ushort4 o;
            o.x = f2bf(acc[j].x);
            o.y = f2bf(acc[j].y);
            o.z = f2bf(acc[j].z);
            o.w = f2bf(acc[j].w);
            mg[(size_t)n * 32 + cx] = o;
        }
    }
}

// ---------------- aggregate + bias + LN + relu + residual (in-place h) ----------------
// one wave per node, split into 2 half-waves; each half gathers a different edge's
// row as uint2 (4 bf16 ch / lane). 8 edges per iteration, 4 accumulators.
__global__ __launch_bounds__(256) void k_agg(const ushort* __restrict__ m,
                                             const int* __restrict__ rowp,
                                             const int2* __restrict__ evrec,
                                             const float* __restrict__ dinv,
                                             const float* __restrict__ cb,
                                             const float* __restrict__ g,
                                             const float* __restrict__ bb,
                                             float* __restrict__ h) {
    int lane = threadIdx.x & 63;
    int sub = lane & 31;           // channel quad: 4*sub..4*sub+3
    int hi = lane >> 5;            // which edge of the pair
    int n = blockIdx.x * 4 + (threadIdx.x >> 6);
    if (n >= NN) return;
    const uint2* mu2 = (const uint2*)m;
    float dn = dinv[n];
    float selfs = hi ? 0.0f : dn * dn;
    float4 sv = bfu2(mu2[(size_t)n * 32 + sub]);
    float4 a0, a1, a2, a3;
    a0.x = selfs * sv.x; a0.y = selfs * sv.y; a0.z = selfs * sv.z; a0.w = selfs * sv.w;
    a1 = make_float4(0, 0, 0, 0);
    a2 = make_float4(0, 0, 0, 0);
    a3 = make_float4(0, 0, 0, 0);
    int r0 = rowp[n], r1 = rowp[n + 1];          // multiples of 8
    const int4* e4 = (const int4*)evrec;
    for (int r = r0; r < r1; r += 8) {
        int qb = r >> 1;
        int4 q0 = e4[qb + 0];                    // edges r, r+1
        int4 q1 = e4[qb + 1];                    // edges r+2, r+3
        int4 q2 = e4[qb + 2];
        int4 q3 = e4[qb + 3];
        int   s0 = hi ? q0.z : q0.x;  float v0 = __int_as_float(hi ? q0.w : q0.y);
        int   s1 = hi ? q1.z : q1.x;  float v1 = __int_as_float(hi ? q1.w : q1.y);
        int   s2 = hi ? q2.z : q2.x;  float v2 = __int_as_float(hi ? q2.w : q2.y);
        int   s3 = hi ? q3.z : q3.x;  float v3 = __int_as_float(hi ? q3.w : q3.y);
        float4 g0 = bfu2(mu2[(size_t)s0 * 32 + sub]);
        float4 g1 = bfu2(mu2[(size_t)s1 * 32 + sub]);
        float4 g2 = bfu2(mu2[(size_t)s2 * 32 + sub]);
        float4 g3 = bfu2(mu2[(size_t)s3 * 32 + sub]);
        a0.x += v0 * g0.x; a0.y += v0 * g0.y; a0.z += v0 * g0.z; a0.w += v0 * g0.w;
        a1.x += v1 * g1.x; a1.y += v1 * g1.y; a1.z += v1 * g1.z; a1.w += v1 * g1.w;
        a2.x += v2 * g2.x; a2.y += v2 * g2.y; a2.z += v2 * g2.z; a2.w += v2 * g2.w;
        a3.x += v3 * g3.x; a3.y += v3 * g3.y; a3.z += v3 * g3.z; a3.w += v3 * g3.w;
    }
    float4 acc;
    acc.x = a0.x + a1.x + a2.x + a3.x;
    acc.y = a0.y + a1.y + a2.y + a3.y;
    acc.z = a0.z + a1.z + a2.z + a3.z;
    acc.w = a0.w + a1.w + a2.w + a3.w;
    // combine the two half-wave partial sums (lane l <-> l^32)
    acc.x += __shfl_xor(acc.x, 32, 64);
    acc.y += __shfl_xor(acc.y, 32, 64);
    acc.z += __shfl_xor(acc.z, 32, 64);
    acc.w += __shfl_xor(acc.w, 32, 64);
    float4 cbv = ((const float4*)cb)[sub];
    acc.x += cbv.x; acc.y += cbv.y; acc.z += cbv.z; acc.w += cbv.w;
    // LayerNorm over 128 channels: reduce across 32 lanes (both halves identical)
    float s1 = acc.x + acc.y + acc.z + acc.w;
    float s2 = acc.x * acc.x + acc.y * acc.y + acc.z * acc.z + acc.w * acc.w;
#pragma unroll
    for (int off = 16; off > 0; off >>= 1) {
        s1 += __shfl_down(s1, off, 32);
        s2 += __shfl_down(s2, off, 32);
    }
    s1 = __shfl(s1, 0, 32);
    s2 = __shfl(s2, 0, 32);
    float mu = s1 * (1.0f / HID);
    float var = s2 * (1.0f / HID) - mu * mu;
    float rs = rsqrtf(var + LN_EPS);
    if (hi == 0) {
        float4 gv = ((const float4*)g)[sub];
        float4 bv = ((const float4*)bb)[sub];
        float4* h4 = (float4*)h;
        float4 hv = h4[(size_t)n * 32 + sub];
        float4 o;
        o.x = fmaxf((acc.x - mu) * rs * gv.x + bv.x, 0.f) + hv.x;
        o.y = fmaxf((acc.y - mu) * rs * gv.y + bv.y, 0.f) + hv.y;
        o.z = fmaxf((acc.z - mu) * rs * gv.z + bv.z, 0.f) + hv.z;
        o.w = fmaxf((acc.w - mu) * rs * gv.w + bv.w, 0.f) + hv.w;
        h4[(size_t)n * 32 + sub] = o;
    }
}

// ---------------- launch ----------------

extern "C" void kernel_launch(void* const* d_in, const int* in_sizes, int n_in,
                              void* d_out, int out_size, void* d_ws, size_t ws_size,
                              hipStream_t stream) {
    const float* x    = (const float*)d_in[0];
    const int*   ei   = (const int*)d_in[1];
    const float* ew   = (const float*)d_in[2];
    const float* W_in = (const float*)d_in[3];
    const float* b_in = (const float*)d_in[4];
    const float* cW   = (const float*)d_in[5];
    const float* cb   = (const float*)d_in[6];
    const float* lg   = (const float*)d_in[7];
    const float* lb   = (const float*)d_in[8];
    float* h = (float*)d_out;

    char* ws = (char*)d_ws;
    unsigned long long* pk = (unsigned long long*)(ws + 0);   // 50000 u64 (cnt|Q20 deg)
    int*    rowp     = (int*)  (ws + 401408);                 // 50001
    int*    rowp_tmp = (int*)  (ws + 602112);
    int*    bsum     = (int*)  (ws + 802816);                 // 64
    int*    boff     = (int*)  (ws + 803072);                 // 64
    int2*   evrec    = (int2*) (ws + 803328);                 // ECAP int2 (9.2 MB)
    ushort* m        = (ushort*)(ws + 10003328);              // 50000*128 bf16 (12.8 MB)
    int*    ord      = (int*)  (ws + 10003328);               // aliases m (dead until gemm)
    float*  dinv     = (float*)(ws + 22803328);               // 50000 f32

    const int NB = (NN + 1023) / 1024;                        // 49

    k_zero<<<(100000 / 4 + 255) / 256, 256, 0, stream>>>((int4*)pk, 100000 / 4);
    k_deg_cnt<<<(NE + 255) / 256, 256, 0, stream>>>(ei, ew, pk, ord);
    k_dinv<<<(NN + 255) / 256, 256, 0, stream>>>(pk, dinv);
    k_scan_a<<<NB, 1024, 0, stream>>>(pk, rowp_tmp, bsum);
    k_scan_b<<<1, 64, 0, stream>>>(bsum, boff, rowp, NB);
    k_scan_c<<<NB, 1024, 0, stream>>>(rowp_tmp, boff, rowp);
    k_pad<<<(NN + 255) / 256, 256, 0, stream>>>(pk, rowp, evrec);
    k_scatter<<<(NE + 255) / 256, 256, 0, stream>>>(ei, ew, dinv, rowp, ord, evrec);

    k_inproj<<<(NN + 63) / 64, 256, 0, stream>>>(x, W_in, b_in, h);

    for (int l = 0; l < NL; l++) {
        k_gemm<<<(NN + 63) / 64, 256, 0, stream>>>(h, cW + l * HID * HID, m);
        k_agg<<<(NN + 3) / 4, 256, 0, stream>>>(m, rowp, evrec, dinv,
                                                cb + l * HID, lg + l * HID, lb + l * HID, h);
    }
}